// Round 6
// baseline (797.896 us; speedup 1.0000x reference)
//
#include <hip/hip_runtime.h>

#define NN 100000
#define NP 100096          // 782 * 128, padded row count
#define EE 300000
#define DIN 128
#define HD  256
#define HD2 512
#define NL  4
#define NG  512
#define BN_EPS 1e-5f

typedef __attribute__((ext_vector_type(8))) short s8v;      // bf16x8 frag (4 VGPRs)
typedef __attribute__((ext_vector_type(4))) float f4v;      // fp32x4 acc

typedef unsigned short ushort_t;

// float -> bf16, round-to-nearest-even
static __device__ inline ushort_t f2bf(float f) {
    unsigned u = __float_as_uint(f);
    unsigned r = (u + 0x7fffu + ((u >> 16) & 1u)) >> 16;
    return (ushort_t)r;
}
static __device__ inline float bf2f(ushort_t h) {
    return __uint_as_float(((unsigned)h) << 16);
}
// bf16 pair unpack from packed u32: low half needs shift, high half mask-only
static __device__ inline float blo(unsigned v) { return __uint_as_float(v << 16); }
static __device__ inline float bhi(unsigned v) { return __uint_as_float(v & 0xffff0000u); }

// accumulate 8 channels of BN+relu'd row segment: A[i] += wg * relu(z*sc+sh)
static __device__ inline void gacc(float* A, const uint4 u,
                                   const float4 s0, const float4 s1,
                                   const float4 h0, const float4 h1, float wg) {
    A[0] += wg * fmaxf(blo(u.x) * s0.x + h0.x, 0.f);
    A[1] += wg * fmaxf(bhi(u.x) * s0.y + h0.y, 0.f);
    A[2] += wg * fmaxf(blo(u.y) * s0.z + h0.z, 0.f);
    A[3] += wg * fmaxf(bhi(u.y) * s0.w + h0.w, 0.f);
    A[4] += wg * fmaxf(blo(u.z) * s1.x + h1.x, 0.f);
    A[5] += wg * fmaxf(bhi(u.z) * s1.y + h1.y, 0.f);
    A[6] += wg * fmaxf(blo(u.w) * s1.z + h1.z, 0.f);
    A[7] += wg * fmaxf(bhi(u.w) * s1.w + h1.w, 0.f);
}

// async global->LDS, 16B per lane; LDS dest = uniform base + lane*16
#define GLOAD_LDS16(g, l) __builtin_amdgcn_global_load_lds( \
    (const __attribute__((address_space(1))) unsigned int*)(const void*)(g), \
    (__attribute__((address_space(3))) unsigned int*)(void*)(l), 16, 0, 0)

// s_waitcnt immediates: vmcnt[3:0] | expcnt(7)<<4 | lgkmcnt(15)<<8 | vmcnt[5:4]<<14
#define WAITCNT_VM8 0xF78
#define WAITCNT_VM4 0xF74
#define WAITCNT_VM0 0xF70

// ---------------------------------------------------------------------------
// bf16 MFMA GEMM (kept for GEMM0 / input projection only).
// Block tile 128x128, BK=32, 4 waves, 3-stage circular LDS pipeline.
// ---------------------------------------------------------------------------
__global__ __launch_bounds__(256) void gemm_bf16(
    const ushort_t* __restrict__ A, int lda,
    const ushort_t* __restrict__ BT, int ldb,
    const float* __restrict__ bias,
    ushort_t* __restrict__ C, int ldc,
    int K, int doRelu,
    int doStats, float* __restrict__ stats, int Mvalid)
{
    extern __shared__ char smem[];
    ushort_t* lds = (ushort_t*)smem;            // 3 stages x (A 8KB | B 8KB)
    ushort_t* Cs  = lds;                        // epilogue reuse (32 KB)
    float* ssum   = (float*)(smem + 49152);     // [4][128]
    float* ssq    = ssum + 512;

    const int tid  = threadIdx.x;
    const int w    = tid >> 6;
    const int L    = tid & 63;
    const int lm   = L & 15;
    const int q    = L >> 4;
    const int row0 = blockIdx.x * 128;
    const int col0 = blockIdx.y * 128;

    const ushort_t* gAbase = A  + (size_t)lm * lda;
    const ushort_t* gBbase = BT + (size_t)lm * ldb;

    f4v acc[2][8] = {};

    const int niter = K >> 5;

    #define STAGE(buf, k0) do {                                              \
        ushort_t* As_ = lds + (buf) * 8192;                                  \
        ushort_t* Bs_ = As_ + 4096;                                          \
        const int kk_ = (k0) + q * 8;                                        \
        _Pragma("unroll")                                                    \
        for (int i_ = 0; i_ < 2; ++i_) {                                     \
            const int tl_ = w * 2 + i_;                                      \
            GLOAD_LDS16(gAbase + (size_t)(row0 + tl_ * 16) * lda + kk_,      \
                        As_ + tl_ * 512);                                    \
            GLOAD_LDS16(gBbase + (size_t)(col0 + tl_ * 16) * ldb + kk_,      \
                        Bs_ + tl_ * 512);                                    \
        }                                                                    \
    } while (0)

    STAGE(0, 0);
    if (niter > 1) STAGE(1, 32);
    if (niter > 2) STAGE(2, 64);

    int cur = 0;
    for (int it = 0; it < niter; ++it) {
        const int rem = niter - 1 - it;
        if (rem >= 2)      __builtin_amdgcn_s_waitcnt(WAITCNT_VM8);
        else if (rem == 1) __builtin_amdgcn_s_waitcnt(WAITCNT_VM4);
        else               __builtin_amdgcn_s_waitcnt(WAITCNT_VM0);
        __builtin_amdgcn_s_barrier();

        const ushort_t* Ab = lds + cur * 8192;
        const ushort_t* Bb = Ab + 4096;
        s8v a0 = *(const s8v*)&Ab[(2 * w)     * 512 + L * 8];
        s8v a1 = *(const s8v*)&Ab[(2 * w + 1) * 512 + L * 8];
#pragma unroll
        for (int nt = 0; nt < 8; ++nt) {
            s8v b = *(const s8v*)&Bb[nt * 512 + L * 8];
            acc[0][nt] = __builtin_amdgcn_mfma_f32_16x16x32_bf16(a0, b, acc[0][nt], 0, 0, 0);
            acc[1][nt] = __builtin_amdgcn_mfma_f32_16x16x32_bf16(a1, b, acc[1][nt], 0, 0, 0);
        }
        __builtin_amdgcn_s_barrier();
        if (it + 3 < niter) STAGE(cur, (it + 3) * 32);
        cur = (cur == 2) ? 0 : cur + 1;
    }
    #undef STAGE

    __syncthreads();

    // epilogue: bias + relu + cvt; C/D frag: col = lm, row = q*4 + r
    float cs[8] = {};
    float cq[8] = {};
#pragma unroll
    for (int mt = 0; mt < 2; ++mt) {
#pragma unroll
        for (int nt = 0; nt < 8; ++nt) {
            const float bj = bias[col0 + nt * 16 + lm];
            f4v v = acc[mt][nt];
#pragma unroll
            for (int r = 0; r < 4; ++r) {
                float f = v[r] + bj;
                if (doRelu) f = fmaxf(f, 0.f);
                const int row = (2 * w + mt) * 16 + q * 4 + r;
                const int col = nt * 16 + lm;
                Cs[row * 128 + col] = f2bf(f);
                if (doStats && (row0 + row) < Mvalid) {
                    cs[nt] += f;
                    cq[nt] += f * f;
                }
            }
        }
    }
    if (doStats) {
#pragma unroll
        for (int nt = 0; nt < 8; ++nt) {
            float s = cs[nt], sq = cq[nt];
            s  += __shfl_xor(s, 16, 64);  s  += __shfl_xor(s, 32, 64);
            sq += __shfl_xor(sq, 16, 64); sq += __shfl_xor(sq, 32, 64);
            cs[nt] = s; cq[nt] = sq;
        }
    }
    __syncthreads();
    if (doStats && q == 0) {
#pragma unroll
        for (int nt = 0; nt < 8; ++nt) {
            ssum[w * 128 + nt * 16 + lm] = cs[nt];
            ssq [w * 128 + nt * 16 + lm] = cq[nt];
        }
    }
#pragma unroll
    for (int i = 0; i < 8; ++i) {
        const int idx = i * 256 + tid;
        const int row = idx >> 4, ch = idx & 15;
        s8v val = *(const s8v*)&Cs[row * 128 + ch * 8];
        *(s8v*)(C + (size_t)(row0 + row) * ldc + col0 + ch * 8) = val;
    }
    if (doStats) {
        __syncthreads();
        if (tid < 128) {
            const float s  = ssum[tid] + ssum[128 + tid] + ssum[256 + tid] + ssum[384 + tid];
            const float sq = ssq[tid]  + ssq[128 + tid]  + ssq[256 + tid]  + ssq[384 + tid];
            unsafeAtomicAdd(&stats[col0 + tid], s);
            unsafeAtomicAdd(&stats[HD + col0 + tid], sq);
        }
    }
}

// ---------------------------------------------------------------------------
// Weight packing into MFMA-fragment order so fused staging is contiguous
// 1KB bursts. Unit = 1KB = [lane L][e 0..7] bf16. Fragment built directly in
// an ext_vector register (no address-taken stack array).
// W1 input [NL][HD][HD2] f32 (in x out). Unit (l, c, u): kk=u>>1, nt=u&1;
//   value = W1[l][kk*32 + (L>>4)*8 + e][c*32 + nt*16 + (L&15)].
__global__ __launch_bounds__(256) void pack_w1_kernel(
    const float* __restrict__ W1, ushort_t* __restrict__ W1P)
{
    const int t = threadIdx.x, L = t & 63;
    const int gu = blockIdx.x * 4 + (t >> 6);      // 0..1023
    const int l = gu >> 8, rem = gu & 255;
    const int c = rem >> 4, u = rem & 15;
    const int kk = u >> 1, nt = u & 1;
    const int h  = c * 32 + nt * 16 + (L & 15);
    const int k0 = kk * 32 + (L >> 4) * 8;
    const float* src = W1 + (size_t)l * HD * HD2;
    s8v v;
#pragma unroll
    for (int e = 0; e < 8; ++e)
        v[e] = (short)f2bf(src[(size_t)(k0 + e) * HD2 + h]);
    *(s8v*)(W1P + (size_t)gu * 512 + L * 8) = v;
}

// W2 input [NL][HD2][HD] f32. Unit (l, c, nt):
//   value = W2[l][c*32 + (L>>4)*8 + e][nt*16 + (L&15)].
__global__ __launch_bounds__(256) void pack_w2_kernel(
    const float* __restrict__ W2, ushort_t* __restrict__ W2P)
{
    const int t = threadIdx.x, L = t & 63;
    const int gu = blockIdx.x * 4 + (t >> 6);      // 0..1023
    const int l = gu >> 8, rem = gu & 255;
    const int c = rem >> 4, nt = rem & 15;
    const int h  = nt * 16 + (L & 15);
    const int k0 = c * 32 + (L >> 4) * 8;
    const float* src = W2 + (size_t)l * HD2 * HD;
    s8v v;
#pragma unroll
    for (int e = 0; e < 8; ++e)
        v[e] = (short)f2bf(src[(size_t)(k0 + e) * HD + h]);
    *(s8v*)(W2P + (size_t)gu * 512 + L * 8) = v;
}

// ---------------------------------------------------------------------------
// Fused GIN LAYER: gather-aggregate (BN+relu on the fly) + MLP + stats.
//   A[n] = (1+eps)*y[n] + sum_{s in nbrs(n)} y[s],  y = relu(z*sc+sh)
//   z' = relu(A @ W1 + b1) @ W2 + b2;  stats += colsum/colsumsq(z')
//
// The chunk loop + epilogue are the v2 structure verbatim (measured 98 us);
// this version replaces the abuf read with an in-kernel gather (4 channel
// passes of 64 ch to bound live registers), eliminating the standalone
// aggregate kernel (~50 us/layer) and the 51MB abuf write + 51MB read.
// z ping-pongs across layers (gather reads zin, epilogue writes zout).
// ---------------------------------------------------------------------------
__global__ __launch_bounds__(512, 4) void fused_layer_kernel(
    const ushort_t* __restrict__ z,      // [NP, HD] bf16 (pre-BN, layer in)
    const int* __restrict__ offs, const int* __restrict__ deg,
    const int* __restrict__ srcSorted,
    const float* __restrict__ epsArr, int epsIdx,
    const float* __restrict__ sscale, const float* __restrict__ sshift,
    const ushort_t* __restrict__ W1l,    // [256 units x 512] packed bf16
    const float*    __restrict__ b1l,    // [HD2]
    const ushort_t* __restrict__ W2l,    // [256 units x 512] packed bf16
    const float*    __restrict__ b2l,    // [HD]
    ushort_t* __restrict__ C,            // [NP, HD] bf16 (pre-BN, layer out)
    float* __restrict__ stats)           // [2*HD] col sum / sumsq (atomic)
{
    extern __shared__ char smem[];
    ushort_t* lds = (ushort_t*)smem;
    const int tid = threadIdx.x;
    const int w   = tid >> 6;            // wave 0..7 -> rows [w*16, w*16+16)
    const int L   = tid & 63;
    const int lm  = L & 15;
    const int q   = L >> 4;
    const int row0 = blockIdx.x * 128;

    // LDS map (bytes): 0..32767 buf0 | 32768..65535 buf1 |
    // 65536..75775 hchunk (8 x 1280) | 75776..77823 b1s | rest spare.
    // Epilogue overlay: Cs 0..65535 | ssum 65536..73727 | ssq 73728..81919.
    float* b1s = (float*)(smem + 75776);
    char*  hcb = smem + 65536 + w * 1280;   // wave-private [16 rows][80B]

    // ---- biases -> LDS (loads drain before the gather's vm0) ----
    b1s[tid] = b1l[tid];
    __syncthreads();

    // ---- fused aggregate: build A-frags a[kk] for row n = row0+w*16+lm ----
    // a[kk] holds channels kk*32 + q*8 .. +7 (the v2 A-frag layout).
    // 4 passes x 64 ch (kk pairs) bound live f32 registers.
    const int n = row0 + w * 16 + lm;
    int estart = 0, edeg = 0;
    if (n < NN) { estart = offs[n]; edeg = deg[n]; }
    const float se = 1.0f + epsArr[epsIdx];
    s8v a[8];
#pragma unroll
    for (int p = 0; p < 4; ++p) {
        const int c0 = (2 * p) * 32 + q * 8;
        const int c1 = c0 + 32;
        const float4 sa0 = *(const float4*)(sscale + c0);
        const float4 sa1 = *(const float4*)(sscale + c0 + 4);
        const float4 ha0 = *(const float4*)(sshift + c0);
        const float4 ha1 = *(const float4*)(sshift + c0 + 4);
        const float4 sb0 = *(const float4*)(sscale + c1);
        const float4 sb1 = *(const float4*)(sscale + c1 + 4);
        const float4 hb0 = *(const float4*)(sshift + c1);
        const float4 hb1 = *(const float4*)(sshift + c1 + 4);
        float A0[8] = {};
        float A1[8] = {};
        if (n < NN) {                    // self, weight (1+eps)
            const uint4 u = *(const uint4*)(z + (size_t)n * HD + c0);
            const uint4 v = *(const uint4*)(z + (size_t)n * HD + c1);
            gacc(A0, u, sa0, sa1, ha0, ha1, se);
            gacc(A1, v, sb0, sb1, hb0, hb1, se);
        }
        for (int j = 0; j < edeg; ++j) { // neighbors, weight 1
            const int s = srcSorted[estart + j];
            const uint4 u = *(const uint4*)(z + (size_t)s * HD + c0);
            const uint4 v = *(const uint4*)(z + (size_t)s * HD + c1);
            gacc(A0, u, sa0, sa1, ha0, ha1, 1.f);
            gacc(A1, v, sb0, sb1, hb0, hb1, 1.f);
        }
        s8v va, vb;
#pragma unroll
        for (int e = 0; e < 8; ++e) {
            va[e] = (short)f2bf(A0[e]);
            vb[e] = (short)f2bf(A1[e]);
        }
        a[2 * p]     = va;
        a[2 * p + 1] = vb;
    }
    __builtin_amdgcn_s_waitcnt(WAITCNT_VM0);   // gather done; vmcnt clean

    // stage chunk cc into buf: 32 contiguous 1KB units, 4 per wave.
    // buf layout (ushorts): W1c at +0 (16 units), W2c at +8192 (16 units).
#define STAGE_W(buf, cc) do {                                                 \
    ushort_t* Wb_ = lds + (buf) * 16384;                                      \
    if (w < 4) {                                                              \
        _Pragma("unroll")                                                     \
        for (int i_ = 0; i_ < 4; ++i_) {                                      \
            const int u_ = w * 4 + i_;                                        \
            GLOAD_LDS16(W1l + ((cc) * 16 + u_) * 512 + L * 8,                 \
                        Wb_ + u_ * 512);                                      \
        }                                                                     \
    } else {                                                                  \
        _Pragma("unroll")                                                     \
        for (int i_ = 0; i_ < 4; ++i_) {                                      \
            const int u_ = (w - 4) * 4 + i_;                                  \
            GLOAD_LDS16(W2l + ((cc) * 16 + u_) * 512 + L * 8,                 \
                        Wb_ + 8192 + u_ * 512);                               \
        }                                                                     \
    }                                                                         \
} while (0)

    STAGE_W(0, 0);
    STAGE_W(1, 1);

    f4v acc2[16] = {};                   // z rows w*16.. x 256 cols
    for (int c = 0; c < 16; ++c) {
        // counted wait: stage(c) landed, stage(c+1)'s 4 loads stay in flight
        if (c < 15) __builtin_amdgcn_s_waitcnt(WAITCNT_VM4);
        else        __builtin_amdgcn_s_waitcnt(WAITCNT_VM0);
        __builtin_amdgcn_s_barrier();
        __builtin_amdgcn_sched_barrier(0);

        const ushort_t* Wb  = lds + (c & 1) * 16384;
        const ushort_t* W2b = Wb + 8192;

        // GEMM1: hchunk = A x W1c  (2 chains x 8 deep)
        f4v acc1[2] = {};
        __builtin_amdgcn_s_setprio(1);
#pragma unroll
        for (int kk = 0; kk < 8; ++kk) {
#pragma unroll
            for (int nt = 0; nt < 2; ++nt) {
                s8v b = *(const s8v*)&Wb[(kk * 2 + nt) * 512 + L * 8];
                acc1[nt] = __builtin_amdgcn_mfma_f32_16x16x32_bf16(a[kk], b, acc1[nt], 0, 0, 0);
            }
        }
        __builtin_amdgcn_s_setprio(0);

        // bias + relu + bf16 -> wave-private LDS [16][80B] (frag transpose)
#pragma unroll
        for (int nt = 0; nt < 2; ++nt) {
            const float bj = b1s[c * 32 + nt * 16 + lm];
#pragma unroll
            for (int r = 0; r < 4; ++r) {
                const int rr = q * 4 + r;
                *(ushort_t*)(hcb + rr * 80 + (nt * 16 + lm) * 2) =
                    f2bf(fmaxf(acc1[nt][r] + bj, 0.f));
            }
        }
        // GEMM2: zacc += hchunk x W2c  (16 independent 1-deep chains)
        const s8v at = *(const s8v*)(hcb + lm * 80 + q * 16);
        __builtin_amdgcn_s_setprio(1);
#pragma unroll
        for (int nt = 0; nt < 16; ++nt) {
            s8v b = *(const s8v*)&W2b[nt * 512 + L * 8];
            acc2[nt] = __builtin_amdgcn_mfma_f32_16x16x32_bf16(at, b, acc2[nt], 0, 0, 0);
        }
        __builtin_amdgcn_s_setprio(0);

        __builtin_amdgcn_sched_barrier(0);
        __builtin_amdgcn_s_barrier();
        if (c + 2 < 16) STAGE_W((c & 1), c + 2);
    }
#undef STAGE_W

    __syncthreads();

    // ---- epilogue: bias + stats + bf16, LDS bounce for coalesced store ----
    ushort_t* Cs = lds;                      // [128][256] bf16, 64KB
    float* ssum  = (float*)(smem + 65536);   // [8][256]
    float* ssq   = (float*)(smem + 73728);   // [8][256]

#pragma unroll
    for (int nt = 0; nt < 16; ++nt) {
        const float bj = b2l[nt * 16 + lm];
        float s = 0.f, sq = 0.f;
#pragma unroll
        for (int r = 0; r < 4; ++r) {
            const float f  = acc2[nt][r] + bj;
            const int row  = w * 16 + q * 4 + r;
            Cs[row * 256 + nt * 16 + lm] = f2bf(f);
            if (row0 + row < NN) { s += f; sq += f * f; }
        }
        s  += __shfl_xor(s, 16, 64);  s  += __shfl_xor(s, 32, 64);
        sq += __shfl_xor(sq, 16, 64); sq += __shfl_xor(sq, 32, 64);
        if (q == 0) {
            ssum[w * 256 + nt * 16 + lm] = s;
            ssq [w * 256 + nt * 16 + lm] = sq;
        }
    }
    __syncthreads();

#pragma unroll
    for (int i = 0; i < 8; ++i) {
        const int idx = i * 512 + tid;       // 16B unit among 4096
        const int row = idx >> 5, ch = idx & 31;
        const s8v v = *(const s8v*)&Cs[idx * 8];
        *(s8v*)(C + (size_t)(row0 + row) * HD + ch * 8) = v;
    }
    if (tid < HD) {
        float s = 0.f, sq = 0.f;
#pragma unroll
        for (int ww = 0; ww < 8; ++ww) {
            s  += ssum[ww * 256 + tid];
            sq += ssq [ww * 256 + tid];
        }
        unsafeAtomicAdd(&stats[tid], s);
        unsafeAtomicAdd(&stats[HD + tid], sq);
    }
}

// ---------------------------------------------------------------------------
// Batched transpose + fp32->bf16: out[z][c][r] = in[z][r][c]; blockIdx.z = batch.
__global__ __launch_bounds__(256) void transpose_cvt_kernel(
    const float* __restrict__ in, ushort_t* __restrict__ out, int R, int C,
    long inStride, long outStride)
{
    __shared__ float tile[32][33];
    const float* inp  = in  + (size_t)blockIdx.z * inStride;
    ushort_t*    outp = out + (size_t)blockIdx.z * outStride;
    const int bx = blockIdx.x * 32;
    const int by = blockIdx.y * 32;
    const int tx = threadIdx.x & 31;
    const int ty = threadIdx.x >> 5;
#pragma unroll
    for (int i = 0; i < 32; i += 8)
        tile[ty + i][tx] = inp[(size_t)(by + ty + i) * C + bx + tx];
    __syncthreads();
#pragma unroll
    for (int i = 0; i < 32; i += 8)
        outp[(size_t)(bx + ty + i) * R + by + tx] = f2bf(tile[tx][ty + i]);
}

__global__ __launch_bounds__(256) void cvt_kernel(
    const float* __restrict__ in, ushort_t* __restrict__ out, long n4)
{
    const long i = (long)blockIdx.x * 256 + threadIdx.x;
    if (i >= n4) return;
    const float4 v = ((const float4*)in)[i];
    ushort4 o;
    o.x = f2bf(v.x); o.y = f2bf(v.y); o.z = f2bf(v.z); o.w = f2bf(v.w);
    ((ushort4*)out)[i] = o;
}

__global__ __launch_bounds__(256) void zero_kernel(float* __restrict__ p, long n4)
{
    const long i = (long)blockIdx.x * 256 + threadIdx.x;
    if (i < n4) ((float4*)p)[i] = make_float4(0.f, 0.f, 0.f, 0.f);
}

// identity scale/shift + zeroed stats (once per call, before layer 0)
__global__ __launch_bounds__(256) void init_bn_kernel(
    float* __restrict__ sscale, float* __restrict__ sshift,
    float* __restrict__ stats)
{
    const int t = threadIdx.x;
    sscale[t] = 1.f;
    sshift[t] = 0.f;
    stats[t] = 0.f;
    stats[HD + t] = 0.f;
}

// scale/shift from stats; re-zero stats for the next layer
__global__ __launch_bounds__(256) void bnprep_kernel(
    float* __restrict__ stats, const float* __restrict__ gamma,
    const float* __restrict__ beta, float* __restrict__ sscale,
    float* __restrict__ sshift, int Nn)
{
    const int t = threadIdx.x;
    const float invN = 1.0f / (float)Nn;
    const float mu  = stats[t] * invN;
    const float var = stats[HD + t] * invN - mu * mu;
    const float inv = rsqrtf(var + BN_EPS);
    const float sc  = gamma[t] * inv;
    sscale[t] = sc;
    sshift[t] = beta[t] - mu * sc;
    stats[t] = 0.f;
    stats[HD + t] = 0.f;
}

// ---------------- CSR build (per call; edges are layer-invariant) -----------
__global__ __launch_bounds__(256) void hist_kernel(
    const int* __restrict__ dst, int* __restrict__ deg, int E)
{
    const int e = blockIdx.x * 256 + threadIdx.x;
    if (e < E) atomicAdd(&deg[dst[e]], 1);
}

__global__ __launch_bounds__(256) void scan1_kernel(
    const int* __restrict__ deg, int* __restrict__ partial,
    int* __restrict__ bsums, int n)
{
    __shared__ int tmp[256];
    const int i = blockIdx.x * 256 + threadIdx.x;
    const int v = (i < n) ? deg[i] : 0;
    tmp[threadIdx.x] = v;
    __syncthreads();
    for (int off = 1; off < 256; off <<= 1) {
        const int t = (threadIdx.x >= off) ? tmp[threadIdx.x - off] : 0;
        __syncthreads();
        tmp[threadIdx.x] += t;
        __syncthreads();
    }
    if (i < n) partial[i] = tmp[threadIdx.x] - v;
    if (threadIdx.x == 255) bsums[blockIdx.x] = tmp[255];
}

__global__ __launch_bounds__(512) void scan2_kernel(int* __restrict__ bsums, int nb)
{
    __shared__ int tmp[512];
    const int i = threadIdx.x;
    const int v = (i < nb) ? bsums[i] : 0;
    tmp[i] = v;
    __syncthreads();
    for (int off = 1; off < 512; off <<= 1) {
        const int t = (i >= off) ? tmp[i - off] : 0;
        __syncthreads();
        tmp[i] += t;
        __syncthreads();
    }
    if (i < nb) bsums[i] = tmp[i] - v;
}

__global__ __launch_bounds__(256) void scan3_kernel(
    const int* __restrict__ partial, const int* __restrict__ bsums,
    int* __restrict__ offs, int* __restrict__ cursor, int n)
{
    const int i = blockIdx.x * 256 + threadIdx.x;
    if (i < n) {
        const int o = partial[i] + bsums[blockIdx.x];
        offs[i] = o;
        cursor[i] = o;
    }
}

__global__ __launch_bounds__(256) void scatter_kernel(
    const int* __restrict__ src, const int* __restrict__ dst,
    int* __restrict__ cursor, int* __restrict__ srcSorted, int E)
{
    const int e = blockIdx.x * 256 + threadIdx.x;
    if (e >= E) return;
    const int p = atomicAdd(&cursor[dst[e]], 1);
    srcSorted[p] = src[e];
}

// ---------------------------------------------------------------------------
// Fused mean-pool + head, BN on the fly.
__global__ __launch_bounds__(256) void pool_head_kernel(
    const ushort_t* __restrict__ z, const int* __restrict__ batch,
    const float* __restrict__ sscale, const float* __restrict__ sshift,
    const float* __restrict__ Wp1, const float* __restrict__ bp1,
    const float* __restrict__ Wp2, const float* __restrict__ bp2,
    float* __restrict__ out)
{
    __shared__ float poolw[4][HD];
    __shared__ float pool[HD];
    __shared__ float red[128];
    __shared__ int seg[2];
    const int g = blockIdx.x;
    const int t = threadIdx.x;
    const int w = t >> 6;
    const int L = t & 63;
    if (t == 0) {
        int lo = 0, hi = NN;
        while (lo < hi) { const int m = (lo + hi) >> 1; if (batch[m] < g) lo = m + 1; else hi = m; }
        seg[0] = lo;
        hi = NN;
        while (lo < hi) { const int m = (lo + hi) >> 1; if (batch[m] < g + 1) lo = m + 1; else hi = m; }
        seg[1] = lo;
    }
    __syncthreads();
    const int start = seg[0], end = seg[1];
    const int c0 = L * 4;
    const float4 sc = *(const float4*)(sscale + c0);
    const float4 sh = *(const float4*)(sshift + c0);
    float a0 = 0.f, a1 = 0.f, a2 = 0.f, a3 = 0.f;
    float b0 = 0.f, b1 = 0.f, b2 = 0.f, b3 = 0.f;
    int r = start + w;
    for (; r + 4 < end; r += 8) {
        const ushort4 u = *(const ushort4*)(z + (size_t)r * HD + c0);
        const ushort4 v = *(const ushort4*)(z + (size_t)(r + 4) * HD + c0);
        a0 += fmaxf(bf2f(u.x) * sc.x + sh.x, 0.f);
        a1 += fmaxf(bf2f(u.y) * sc.y + sh.y, 0.f);
        a2 += fmaxf(bf2f(u.z) * sc.z + sh.z, 0.f);
        a3 += fmaxf(bf2f(u.w) * sc.w + sh.w, 0.f);
        b0 += fmaxf(bf2f(v.x) * sc.x + sh.x, 0.f);
        b1 += fmaxf(bf2f(v.y) * sc.y + sh.y, 0.f);
        b2 += fmaxf(bf2f(v.z) * sc.z + sh.z, 0.f);
        b3 += fmaxf(bf2f(v.w) * sc.w + sh.w, 0.f);
    }
    if (r < end) {
        const ushort4 u = *(const ushort4*)(z + (size_t)r * HD + c0);
        a0 += fmaxf(bf2f(u.x) * sc.x + sh.x, 0.f);
        a1 += fmaxf(bf2f(u.y) * sc.y + sh.y, 0.f);
        a2 += fmaxf(bf2f(u.z) * sc.z + sh.z, 0.f);
        a3 += fmaxf(bf2f(u.w) * sc.w + sh.w, 0.f);
    }
    poolw[w][c0 + 0] = a0 + b0;
    poolw[w][c0 + 1] = a1 + b1;
    poolw[w][c0 + 2] = a2 + b2;
    poolw[w][c0 + 3] = a3 + b3;
    __syncthreads();
    const float invC = 1.0f / (float)max(end - start, 1);
    pool[t] = (poolw[0][t] + poolw[1][t] + poolw[2][t] + poolw[3][t]) * invC;
    __syncthreads();
    if (t < 128) {
        float acc = 0.f;
#pragma unroll 4
        for (int k = 0; k < HD; ++k)
            acc += pool[k] * Wp1[k * 128 + t];
        red[t] = fmaxf(acc + bp1[t], 0.f) * Wp2[t];
    }
    __syncthreads();
    for (int sft = 64; sft > 0; sft >>= 1) {
        if (t < sft) red[t] += red[t + sft];
        __syncthreads();
    }
    if (t == 0) out[g] = red[0] + bp2[0];
}

// ---------------------------------------------------------------------------
extern "C" void kernel_launch(void* const* d_in, const int* in_sizes, int n_in,
                              void* d_out, int out_size, void* d_ws, size_t ws_size,
                              hipStream_t stream)
{
    const float* x     = (const float*)d_in[0];
    const int*   ei    = (const int*)  d_in[1];
    const int*   batch = (const int*)  d_in[2];
    const float* W_in  = (const float*)d_in[3];
    const float* b_in  = (const float*)d_in[4];
    const float* eps   = (const float*)d_in[5];
    const float* W1    = (const float*)d_in[6];
    const float* b1    = (const float*)d_in[7];
    const float* W2    = (const float*)d_in[8];
    const float* b2    = (const float*)d_in[9];
    const float* gamma = (const float*)d_in[10];
    const float* beta  = (const float*)d_in[11];
    const float* Wp1   = (const float*)d_in[12];
    const float* bp1   = (const float*)d_in[13];
    const float* Wp2   = (const float*)d_in[14];
    const float* bp2   = (const float*)d_in[15];

    const int* srcIdx = ei;
    const int* dstIdx = ei + EE;

    // ---- workspace layout ----
    char* p = (char*)d_ws;
    ushort_t* zbuf    = (ushort_t*)p;  p += (size_t)NP * HD  * 2;   // z ping
    ushort_t* zalt    = (ushort_t*)p;  p += (size_t)NP * HD  * 2;   // z pong
    ushort_t* hidden  = (ushort_t*)p;  p += (size_t)NP * HD2 * 2;   // x_bf alias (GEMM0 A)
    ushort_t* W1P     = (ushort_t*)p;  p += (size_t)NL * HD2 * HD * 2;   // packed
    ushort_t* W2P     = (ushort_t*)p;  p += (size_t)NL * HD * HD2 * 2;   // packed
    ushort_t* WinT    = (ushort_t*)p;  p += (size_t)HD * DIN * 2;
    int* deg          = (int*)p;       p += (size_t)NN * 4;
    int* partial      = (int*)p;       p += (size_t)NN * 4;
    int* bsums        = (int*)p;       p += 512 * 4;
    int* offs         = (int*)p;       p += (size_t)NN * 4;
    int* cursor       = (int*)p;       p += (size_t)NN * 4;
    int* srcSorted    = (int*)p;       p += (size_t)EE * 4;
    float* stats      = (float*)p;     p += 2 * HD * 4;
    float* sscale     = (float*)p;     p += HD * 4;
    float* sshift     = (float*)p;     p += HD * 4;
    ushort_t* x_bf    = hidden;        // GEMM0 A

    const int nb = (NN + 255) / 256;   // 391
    const int GEMM_LDS  = 53248;       // gemm_bf16: 3 x 16KB stages + 4KB stats
    const int FUSED_LDS = 81920;       // fused_layer: 64KB W dbuf + 10 hchunk + 2 bias (+epilogue overlay)

    // ---- BN identity + stats zero ----
    init_bn_kernel<<<1, 256, 0, stream>>>(sscale, sshift, stats);

    // ---- weight conversion (Win transposed bf16; W1/W2 packed frag-order) --
    transpose_cvt_kernel<<<dim3(HD / 32, DIN / 32, 1), 256, 0, stream>>>(
        W_in, WinT, DIN, HD, 0, 0);
    pack_w1_kernel<<<256, 256, 0, stream>>>(W1, W1P);
    pack_w2_kernel<<<256, 256, 0, stream>>>(W2, W2P);
    cvt_kernel<<<(int)(((long)NN * DIN / 4 + 255) / 256), 256, 0, stream>>>(
        x, x_bf, (long)NN * DIN / 4);

    // ---- CSR build (once; edges layer-invariant) ----
    zero_kernel<<<(NN / 4 + 255) / 256, 256, 0, stream>>>((float*)deg, NN / 4);
    hist_kernel<<<(EE + 255) / 256, 256, 0, stream>>>(dstIdx, deg, EE);
    scan1_kernel<<<nb, 256, 0, stream>>>(deg, partial, bsums, NN);
    scan2_kernel<<<1, 512, 0, stream>>>(bsums, nb);
    scan3_kernel<<<nb, 256, 0, stream>>>(partial, bsums, offs, cursor, NN);
    scatter_kernel<<<(EE + 255) / 256, 256, 0, stream>>>(srcIdx, dstIdx, cursor, srcSorted, EE);

    // ---- input projection: zbuf = relu(x @ W_in + b_in)  (identity BN) ----
    gemm_bf16<<<dim3(NP / 128, HD / 128), 256, GEMM_LDS, stream>>>(
        x_bf, DIN, WinT, DIN, b_in, zbuf, HD, DIN, 1, 0, nullptr, 0);

    // ---- GIN layers: fused gather+MLP (+stats) -> BN prep; z ping-pongs ----
    const ushort_t* zin = zbuf;
    ushort_t*       zout = zalt;
    for (int l = 0; l < NL; ++l) {
        fused_layer_kernel<<<NP / 128, 512, FUSED_LDS, stream>>>(
            zin, offs, deg, srcSorted, eps, l, sscale, sshift,
            W1P + (size_t)l * HD2 * HD, b1 + (size_t)l * HD2,
            W2P + (size_t)l * HD * HD2, b2 + (size_t)l * HD, zout, stats);

        bnprep_kernel<<<1, 256, 0, stream>>>(
            stats, gamma + (size_t)l * HD, beta + (size_t)l * HD, sscale, sshift, NN);

        const ushort_t* t = zin;
        zin = zout;
        zout = (ushort_t*)t;
    }

    // ---- fused mean pool + head (BN on the fly); zin = zbuf after 4 swaps --
    pool_head_kernel<<<NG, 256, 0, stream>>>(zin, batch, sscale, sshift,
                                             Wp1, bp1, Wp2, bp2, (float*)d_out);
}

// Round 7
// 726.593 us; speedup vs baseline: 1.0981x; 1.0981x over previous
//
#include <hip/hip_runtime.h>

#define NN 100000
#define NP 100096          // 782 * 128, padded row count
#define EE 300000
#define DIN 128
#define HD  256
#define HD2 512
#define NL  4
#define NG  512
#define BN_EPS 1e-5f

typedef __attribute__((ext_vector_type(8))) short s8v;      // bf16x8 frag (4 VGPRs)
typedef __attribute__((ext_vector_type(4))) float f4v;      // fp32x4 acc

typedef unsigned short ushort_t;

// float -> bf16, round-to-nearest-even
static __device__ inline ushort_t f2bf(float f) {
    unsigned u = __float_as_uint(f);
    unsigned r = (u + 0x7fffu + ((u >> 16) & 1u)) >> 16;
    return (ushort_t)r;
}
static __device__ inline float bf2f(ushort_t h) {
    return __uint_as_float(((unsigned)h) << 16);
}
// bf16 pair unpack from packed u32: low half needs shift, high half mask-only
static __device__ inline float blo(unsigned v) { return __uint_as_float(v << 16); }
static __device__ inline float bhi(unsigned v) { return __uint_as_float(v & 0xffff0000u); }

// async global->LDS, 16B per lane; LDS dest = uniform base + lane*16
#define GLOAD_LDS16(g, l) __builtin_amdgcn_global_load_lds( \
    (const __attribute__((address_space(1))) unsigned int*)(const void*)(g), \
    (__attribute__((address_space(3))) unsigned int*)(void*)(l), 16, 0, 0)

// s_waitcnt immediates: vmcnt[3:0] | expcnt(7)<<4 | lgkmcnt(15)<<8 | vmcnt[5:4]<<14
#define WAITCNT_VM8 0xF78
#define WAITCNT_VM4 0xF74
#define WAITCNT_VM0 0xF70

// ---------------------------------------------------------------------------
// Weight packing into MFMA-fragment order so staging is contiguous 1KB
// bursts. Unit = 1KB = [lane L][e 0..7] bf16. Fragment built directly in an
// ext_vector register (no address-taken stack array).
// W1 input [NL][HD][HD2] f32 (in x out). Unit (l, c, u): kk=u>>1, nt=u&1;
//   value = W1[l][kk*32 + (L>>4)*8 + e][c*32 + nt*16 + (L&15)].
__global__ __launch_bounds__(256) void pack_w1_kernel(
    const float* __restrict__ W1, ushort_t* __restrict__ W1P)
{
    const int t = threadIdx.x, L = t & 63;
    const int gu = blockIdx.x * 4 + (t >> 6);      // 0..1023
    const int l = gu >> 8, rem = gu & 255;
    const int c = rem >> 4, u = rem & 15;
    const int kk = u >> 1, nt = u & 1;
    const int h  = c * 32 + nt * 16 + (L & 15);
    const int k0 = kk * 32 + (L >> 4) * 8;
    const float* src = W1 + (size_t)l * HD * HD2;
    s8v v;
#pragma unroll
    for (int e = 0; e < 8; ++e)
        v[e] = (short)f2bf(src[(size_t)(k0 + e) * HD2 + h]);
    *(s8v*)(W1P + (size_t)gu * 512 + L * 8) = v;
}

// W2 input [NL][HD2][HD] f32. Unit (l, c, nt):
//   value = W2[l][c*32 + (L>>4)*8 + e][nt*16 + (L&15)].
__global__ __launch_bounds__(256) void pack_w2_kernel(
    const float* __restrict__ W2, ushort_t* __restrict__ W2P)
{
    const int t = threadIdx.x, L = t & 63;
    const int gu = blockIdx.x * 4 + (t >> 6);      // 0..1023
    const int l = gu >> 8, rem = gu & 255;
    const int c = rem >> 4, nt = rem & 15;
    const int h  = nt * 16 + (L & 15);
    const int k0 = c * 32 + (L >> 4) * 8;
    const float* src = W2 + (size_t)l * HD2 * HD;
    s8v v;
#pragma unroll
    for (int e = 0; e < 8; ++e)
        v[e] = (short)f2bf(src[(size_t)(k0 + e) * HD + h]);
    *(s8v*)(W2P + (size_t)gu * 512 + L * 8) = v;
}

// W_in input [DIN][HD] f32 (in x out), 64 units (kk=u>>4 in [0,4), nt=u&15):
//   value = Win[kk*32 + (L>>4)*8 + e][nt*16 + (L&15)].
__global__ __launch_bounds__(256) void pack_win_kernel(
    const float* __restrict__ Win, ushort_t* __restrict__ WinP)
{
    const int t = threadIdx.x, L = t & 63;
    const int gu = blockIdx.x * 4 + (t >> 6);      // 0..63
    const int kk = gu >> 4, nt = gu & 15;
    const int h  = nt * 16 + (L & 15);
    const int k0 = kk * 32 + (L >> 4) * 8;
    s8v v;
#pragma unroll
    for (int e = 0; e < 8; ++e)
        v[e] = (short)f2bf(Win[(size_t)(k0 + e) * HD + h]);
    *(s8v*)(WinP + (size_t)gu * 512 + L * 8) = v;
}

// ---------------------------------------------------------------------------
// Input projection: z = relu(x @ W_in + b_in). W_in (64KB packed) is fully
// LDS-resident: stage once, no inner barriers, 64 MFMAs/wave. Reads x in f32
// directly (in-register cvt) — removes the separate cvt pass.
// 8 waves x 16 rows = 128 rows/block, grid NP/128. LDS 64KB -> 2 blocks/CU.
// ---------------------------------------------------------------------------
__global__ __launch_bounds__(512, 2) void inproj_kernel(
    const float* __restrict__ x,        // [NN, DIN] f32
    const ushort_t* __restrict__ WinP,  // [64 units x 512] packed bf16
    const float* __restrict__ bias,     // [HD]
    ushort_t* __restrict__ C)           // [NP, HD] bf16
{
    extern __shared__ char smem[];
    ushort_t* Ws = (ushort_t*)smem;     // 64 KB, epilogue-overlaid as Cs
    const int tid = threadIdx.x;
    const int w   = tid >> 6;
    const int L   = tid & 63;
    const int lm  = L & 15;
    const int q   = L >> 4;
    const int row0 = blockIdx.x * 128;

    // stage all 64 weight units (8 per wave), one contiguous 1KB burst each
#pragma unroll
    for (int i = 0; i < 8; ++i) {
        const int u = w * 8 + i;
        GLOAD_LDS16(WinP + u * 512 + L * 8, Ws + u * 512);
    }

    // A-frags from x (f32 -> bf16 in-register); clamp padded rows (x is NN rows)
    const int row = row0 + w * 16 + lm;
    const float* xr = x + (size_t)min(row, NN - 1) * DIN;
    s8v a[4];
#pragma unroll
    for (int kk = 0; kk < 4; ++kk) {
        const float4 u0 = *(const float4*)(xr + kk * 32 + q * 8);
        const float4 u1 = *(const float4*)(xr + kk * 32 + q * 8 + 4);
        s8v v;
        v[0] = (short)f2bf(u0.x); v[1] = (short)f2bf(u0.y);
        v[2] = (short)f2bf(u0.z); v[3] = (short)f2bf(u0.w);
        v[4] = (short)f2bf(u1.x); v[5] = (short)f2bf(u1.y);
        v[6] = (short)f2bf(u1.z); v[7] = (short)f2bf(u1.w);
        a[kk] = v;
    }
    __builtin_amdgcn_s_waitcnt(WAITCNT_VM0);
    __syncthreads();

    f4v acc[16] = {};
#pragma unroll
    for (int kk = 0; kk < 4; ++kk) {
#pragma unroll
        for (int nt = 0; nt < 16; ++nt) {
            s8v b = *(const s8v*)&Ws[(kk * 16 + nt) * 512 + L * 8];
            acc[nt] = __builtin_amdgcn_mfma_f32_16x16x32_bf16(a[kk], b, acc[nt], 0, 0, 0);
        }
    }
    __syncthreads();

    // epilogue: bias + relu + bf16 via LDS bounce for coalesced 16B stores
    ushort_t* Cs = Ws;
#pragma unroll
    for (int nt = 0; nt < 16; ++nt) {
        const float bj = bias[nt * 16 + lm];
#pragma unroll
        for (int r = 0; r < 4; ++r) {
            const int rr = w * 16 + q * 4 + r;
            Cs[rr * 256 + nt * 16 + lm] = f2bf(fmaxf(acc[nt][r] + bj, 0.f));
        }
    }
    __syncthreads();
#pragma unroll
    for (int i = 0; i < 8; ++i) {
        const int idx = i * 512 + tid;       // 16B unit among 4096
        const int rr = idx >> 5, ch = idx & 31;
        const s8v v = *(const s8v*)&Cs[idx * 8];
        *(s8v*)(C + (size_t)(row0 + rr) * HD + ch * 8) = v;
    }
}

// ---------------------------------------------------------------------------
// Fused GIN MLP v2 (round-3 measured optimum, 98 us):
// z = (agg @ W1 + b1).relu() @ W2 + b2, plus column stats.
//  - chunk = 32 hidden cols (16 chunks); W stage dbuf 64KB; hchunk 8x1.25KB;
//    bias 2KB -> 80KB LDS => 2 blocks/CU.
//  - counted vmcnt(4): one chunk always in flight; biases pre-staged to LDS.
//  - weights pre-packed so each global_load_lds is one contiguous 1KB burst.
//  - s_setprio around MFMA clusters.
// ---------------------------------------------------------------------------
__global__ __launch_bounds__(512, 4) void fused_mlp_kernel(
    const ushort_t* __restrict__ A,      // [NP, HD] bf16 (aggregate out)
    const ushort_t* __restrict__ W1l,    // [256 units x 512] packed bf16
    const float*    __restrict__ b1l,    // [HD2]
    const ushort_t* __restrict__ W2l,    // [256 units x 512] packed bf16
    const float*    __restrict__ b2l,    // [HD]
    ushort_t* __restrict__ C,            // [NP, HD] bf16 (pre-BN z)
    float* __restrict__ stats)           // [2*HD] col sum / sumsq (atomic)
{
    extern __shared__ char smem[];
    ushort_t* lds = (ushort_t*)smem;
    const int tid = threadIdx.x;
    const int w   = tid >> 6;            // wave 0..7 -> rows [w*16, w*16+16)
    const int L   = tid & 63;
    const int lm  = L & 15;
    const int q   = L >> 4;
    const int row0 = blockIdx.x * 128;

    // LDS map (bytes): 0..32767 buf0 | 32768..65535 buf1 |
    // 65536..75775 hchunk (8 x 1280) | 75776..77823 b1s | rest spare.
    // Epilogue overlay: Cs 0..65535 | ssum 65536..73727 | ssq 73728..81919.
    float* b1s = (float*)(smem + 75776);
    char*  hcb = smem + 65536 + w * 1280;   // wave-private [16 rows][80B]

    // ---- biases -> LDS (consumed before the syncthreads drains vmcnt) ----
    if (tid < HD2) b1s[tid] = b1l[tid];
    __syncthreads();

    // ---- A slice in registers: a[kk] = A-frag for k-step kk (K=256) ----
    const ushort_t* Arow = A + (size_t)(row0 + w * 16 + lm) * HD;
    s8v a[8];
#pragma unroll
    for (int kk = 0; kk < 8; ++kk)
        a[kk] = *(const s8v*)(Arow + kk * 32 + q * 8);
    __builtin_amdgcn_s_waitcnt(WAITCNT_VM0);   // a[] resident; vmcnt clean

    // stage chunk cc into buf: 32 contiguous 1KB units, 4 per wave.
    // buf layout (ushorts): W1c at +0 (16 units), W2c at +8192 (16 units).
#define STAGE_W(buf, cc) do {                                                 \
    ushort_t* Wb_ = lds + (buf) * 16384;                                      \
    if (w < 4) {                                                              \
        _Pragma("unroll")                                                     \
        for (int i_ = 0; i_ < 4; ++i_) {                                      \
            const int u_ = w * 4 + i_;                                        \
            GLOAD_LDS16(W1l + ((cc) * 16 + u_) * 512 + L * 8,                 \
                        Wb_ + u_ * 512);                                      \
        }                                                                     \
    } else {                                                                  \
        _Pragma("unroll")                                                     \
        for (int i_ = 0; i_ < 4; ++i_) {                                      \
            const int u_ = (w - 4) * 4 + i_;                                  \
            GLOAD_LDS16(W2l + ((cc) * 16 + u_) * 512 + L * 8,                 \
                        Wb_ + 8192 + u_ * 512);                               \
        }                                                                     \
    }                                                                         \
} while (0)

    STAGE_W(0, 0);
    STAGE_W(1, 1);

    f4v acc2[16] = {};                   // z rows w*16.. x 256 cols
    for (int c = 0; c < 16; ++c) {
        // counted wait: stage(c) landed, stage(c+1)'s 4 loads stay in flight
        if (c < 15) __builtin_amdgcn_s_waitcnt(WAITCNT_VM4);
        else        __builtin_amdgcn_s_waitcnt(WAITCNT_VM0);
        __builtin_amdgcn_s_barrier();
        __builtin_amdgcn_sched_barrier(0);

        const ushort_t* Wb  = lds + (c & 1) * 16384;
        const ushort_t* W2b = Wb + 8192;

        // GEMM1: hchunk = A x W1c  (2 chains x 8 deep)
        f4v acc1[2] = {};
        __builtin_amdgcn_s_setprio(1);
#pragma unroll
        for (int kk = 0; kk < 8; ++kk) {
#pragma unroll
            for (int nt = 0; nt < 2; ++nt) {
                s8v b = *(const s8v*)&Wb[(kk * 2 + nt) * 512 + L * 8];
                acc1[nt] = __builtin_amdgcn_mfma_f32_16x16x32_bf16(a[kk], b, acc1[nt], 0, 0, 0);
            }
        }
        __builtin_amdgcn_s_setprio(0);

        // bias + relu + bf16 -> wave-private LDS [16][80B] (frag transpose)
#pragma unroll
        for (int nt = 0; nt < 2; ++nt) {
            const float bj = b1s[c * 32 + nt * 16 + lm];
#pragma unroll
            for (int r = 0; r < 4; ++r) {
                const int rr = q * 4 + r;
                *(ushort_t*)(hcb + rr * 80 + (nt * 16 + lm) * 2) =
                    f2bf(fmaxf(acc1[nt][r] + bj, 0.f));
            }
        }
        // GEMM2: zacc += hchunk x W2c  (16 independent 1-deep chains)
        const s8v at = *(const s8v*)(hcb + lm * 80 + q * 16);
        __builtin_amdgcn_s_setprio(1);
#pragma unroll
        for (int nt = 0; nt < 16; ++nt) {
            s8v b = *(const s8v*)&W2b[nt * 512 + L * 8];
            acc2[nt] = __builtin_amdgcn_mfma_f32_16x16x32_bf16(at, b, acc2[nt], 0, 0, 0);
        }
        __builtin_amdgcn_s_setprio(0);

        __builtin_amdgcn_sched_barrier(0);
        __builtin_amdgcn_s_barrier();
        if (c + 2 < 16) STAGE_W((c & 1), c + 2);
    }
#undef STAGE_W

    __syncthreads();

    // ---- epilogue: bias + stats + bf16, LDS bounce for coalesced store ----
    ushort_t* Cs = lds;                      // [128][256] bf16, 64KB
    float* ssum  = (float*)(smem + 65536);   // [8][256]
    float* ssq   = (float*)(smem + 73728);   // [8][256]

#pragma unroll
    for (int nt = 0; nt < 16; ++nt) {
        const float bj = b2l[nt * 16 + lm];
        float s = 0.f, sq = 0.f;
#pragma unroll
        for (int r = 0; r < 4; ++r) {
            const float f  = acc2[nt][r] + bj;
            const int row  = w * 16 + q * 4 + r;
            Cs[row * 256 + nt * 16 + lm] = f2bf(f);
            if (row0 + row < NN) { s += f; sq += f * f; }
        }
        s  += __shfl_xor(s, 16, 64);  s  += __shfl_xor(s, 32, 64);
        sq += __shfl_xor(sq, 16, 64); sq += __shfl_xor(sq, 32, 64);
        if (q == 0) {
            ssum[w * 256 + nt * 16 + lm] = s;
            ssq [w * 256 + nt * 16 + lm] = sq;
        }
    }
    __syncthreads();

#pragma unroll
    for (int i = 0; i < 8; ++i) {
        const int idx = i * 512 + tid;       // 16B unit among 4096
        const int row = idx >> 5, ch = idx & 31;
        const s8v v = *(const s8v*)&Cs[idx * 8];
        *(s8v*)(C + (size_t)(row0 + row) * HD + ch * 8) = v;
    }
    if (tid < HD) {
        float s = 0.f, sq = 0.f;
#pragma unroll
        for (int ww = 0; ww < 8; ++ww) {
            s  += ssum[ww * 256 + tid];
            sq += ssq [ww * 256 + tid];
        }
        unsafeAtomicAdd(&stats[tid], s);
        unsafeAtomicAdd(&stats[HD + tid], sq);
    }
}

__global__ __launch_bounds__(256) void zero_kernel(float* __restrict__ p, long n4)
{
    const long i = (long)blockIdx.x * 256 + threadIdx.x;
    if (i < n4) ((float4*)p)[i] = make_float4(0.f, 0.f, 0.f, 0.f);
}

// identity scale/shift + zeroed stats (once per call, before layer 0)
__global__ __launch_bounds__(256) void init_bn_kernel(
    float* __restrict__ sscale, float* __restrict__ sshift,
    float* __restrict__ stats)
{
    const int t = threadIdx.x;
    sscale[t] = 1.f;
    sshift[t] = 0.f;
    stats[t] = 0.f;
    stats[HD + t] = 0.f;
}

// scale/shift from stats; re-zero stats for the next layer
__global__ __launch_bounds__(256) void bnprep_kernel(
    float* __restrict__ stats, const float* __restrict__ gamma,
    const float* __restrict__ beta, float* __restrict__ sscale,
    float* __restrict__ sshift, int Nn)
{
    const int t = threadIdx.x;
    const float invN = 1.0f / (float)Nn;
    const float mu  = stats[t] * invN;
    const float var = stats[HD + t] * invN - mu * mu;
    const float inv = rsqrtf(var + BN_EPS);
    const float sc  = gamma[t] * inv;
    sscale[t] = sc;
    sshift[t] = beta[t] - mu * sc;
    stats[t] = 0.f;
    stats[HD + t] = 0.f;
}

// ---------------- CSR build (per call; edges are layer-invariant) -----------
__global__ __launch_bounds__(256) void hist_kernel(
    const int* __restrict__ dst, int* __restrict__ deg, int E)
{
    const int e = blockIdx.x * 256 + threadIdx.x;
    if (e < E) atomicAdd(&deg[dst[e]], 1);
}

__global__ __launch_bounds__(256) void scan1_kernel(
    const int* __restrict__ deg, int* __restrict__ partial,
    int* __restrict__ bsums, int n)
{
    __shared__ int tmp[256];
    const int i = blockIdx.x * 256 + threadIdx.x;
    const int v = (i < n) ? deg[i] : 0;
    tmp[threadIdx.x] = v;
    __syncthreads();
    for (int off = 1; off < 256; off <<= 1) {
        const int t = (threadIdx.x >= off) ? tmp[threadIdx.x - off] : 0;
        __syncthreads();
        tmp[threadIdx.x] += t;
        __syncthreads();
    }
    if (i < n) partial[i] = tmp[threadIdx.x] - v;
    if (threadIdx.x == 255) bsums[blockIdx.x] = tmp[255];
}

__global__ __launch_bounds__(512) void scan2_kernel(int* __restrict__ bsums, int nb)
{
    __shared__ int tmp[512];
    const int i = threadIdx.x;
    const int v = (i < nb) ? bsums[i] : 0;
    tmp[i] = v;
    __syncthreads();
    for (int off = 1; off < 512; off <<= 1) {
        const int t = (i >= off) ? tmp[i - off] : 0;
        __syncthreads();
        tmp[i] += t;
        __syncthreads();
    }
    if (i < nb) bsums[i] = tmp[i] - v;
}

__global__ __launch_bounds__(256) void scan3_kernel(
    const int* __restrict__ partial, const int* __restrict__ bsums,
    int* __restrict__ offs, int* __restrict__ cursor, int n)
{
    const int i = blockIdx.x * 256 + threadIdx.x;
    if (i < n) {
        const int o = partial[i] + bsums[blockIdx.x];
        offs[i] = o;
        cursor[i] = o;
    }
}

__global__ __launch_bounds__(256) void scatter_kernel(
    const int* __restrict__ src, const int* __restrict__ dst,
    int* __restrict__ cursor, int* __restrict__ srcSorted, int E)
{
    const int e = blockIdx.x * 256 + threadIdx.x;
    if (e >= E) return;
    const int p = atomicAdd(&cursor[dst[e]], 1);
    srcSorted[p] = src[e];
}

// ---------------------------------------------------------------------------
// out[n] = bf16( (1+eps)*y[n] + sum_{s in nbrs(n)} y[s] ),
// y[i] = relu( z[i]*sscale + sshift )  (BN on the fly).
__global__ __launch_bounds__(256) void aggregate_kernel(
    const ushort_t* __restrict__ z, const int* __restrict__ offs,
    const int* __restrict__ deg, const int* __restrict__ srcSorted,
    const float* __restrict__ epsArr, int epsIdx,
    const float* __restrict__ sscale, const float* __restrict__ sshift,
    ushort_t* __restrict__ out)
{
    const int n = blockIdx.x * 8 + (threadIdx.x >> 5);   // 8 nodes / 256 thr
    const int L = threadIdx.x & 31;
    const int c0 = L * 8;
    const float4 scA = *(const float4*)(sscale + c0);
    const float4 scB = *(const float4*)(sscale + c0 + 4);
    const float4 shA = *(const float4*)(sshift + c0);
    const float4 shB = *(const float4*)(sshift + c0 + 4);
    const int start = offs[n];
    const int dc = deg[n];
    float a[8] = {};
    float b[8] = {};
    int j = 0;
    for (; j + 1 < dc; j += 2) {
        const int s0 = srcSorted[start + j];
        const int s1 = srcSorted[start + j + 1];
        const uint4 u = *(const uint4*)(z + (size_t)s0 * HD + c0);
        const uint4 v = *(const uint4*)(z + (size_t)s1 * HD + c0);
        a[0] += fmaxf(blo(u.x) * scA.x + shA.x, 0.f);
        a[1] += fmaxf(bhi(u.x) * scA.y + shA.y, 0.f);
        a[2] += fmaxf(blo(u.y) * scA.z + shA.z, 0.f);
        a[3] += fmaxf(bhi(u.y) * scA.w + shA.w, 0.f);
        a[4] += fmaxf(blo(u.z) * scB.x + shB.x, 0.f);
        a[5] += fmaxf(bhi(u.z) * scB.y + shB.y, 0.f);
        a[6] += fmaxf(blo(u.w) * scB.z + shB.z, 0.f);
        a[7] += fmaxf(bhi(u.w) * scB.w + shB.w, 0.f);
        b[0] += fmaxf(blo(v.x) * scA.x + shA.x, 0.f);
        b[1] += fmaxf(bhi(v.x) * scA.y + shA.y, 0.f);
        b[2] += fmaxf(blo(v.y) * scA.z + shA.z, 0.f);
        b[3] += fmaxf(bhi(v.y) * scA.w + shA.w, 0.f);
        b[4] += fmaxf(blo(v.z) * scB.x + shB.x, 0.f);
        b[5] += fmaxf(bhi(v.z) * scB.y + shB.y, 0.f);
        b[6] += fmaxf(blo(v.w) * scB.z + shB.z, 0.f);
        b[7] += fmaxf(bhi(v.w) * scB.w + shB.w, 0.f);
    }
    if (j < dc) {
        const int s0 = srcSorted[start + j];
        const uint4 u = *(const uint4*)(z + (size_t)s0 * HD + c0);
        a[0] += fmaxf(blo(u.x) * scA.x + shA.x, 0.f);
        a[1] += fmaxf(bhi(u.x) * scA.y + shA.y, 0.f);
        a[2] += fmaxf(blo(u.y) * scA.z + shA.z, 0.f);
        a[3] += fmaxf(bhi(u.y) * scA.w + shA.w, 0.f);
        a[4] += fmaxf(blo(u.z) * scB.x + shB.x, 0.f);
        a[5] += fmaxf(bhi(u.z) * scB.y + shB.y, 0.f);
        a[6] += fmaxf(blo(u.w) * scB.z + shB.z, 0.f);
        a[7] += fmaxf(bhi(u.w) * scB.w + shB.w, 0.f);
    }
#pragma unroll
    for (int k = 0; k < 8; ++k) a[k] += b[k];
    const float se = 1.0f + epsArr[epsIdx];
    const uint4 hs = *(const uint4*)(z + (size_t)n * HD + c0);
    float y[8];
    y[0] = se * fmaxf(blo(hs.x) * scA.x + shA.x, 0.f) + a[0];
    y[1] = se * fmaxf(bhi(hs.x) * scA.y + shA.y, 0.f) + a[1];
    y[2] = se * fmaxf(blo(hs.y) * scA.z + shA.z, 0.f) + a[2];
    y[3] = se * fmaxf(bhi(hs.y) * scA.w + shA.w, 0.f) + a[3];
    y[4] = se * fmaxf(blo(hs.z) * scB.x + shB.x, 0.f) + a[4];
    y[5] = se * fmaxf(bhi(hs.z) * scB.y + shB.y, 0.f) + a[5];
    y[6] = se * fmaxf(blo(hs.w) * scB.z + shB.z, 0.f) + a[6];
    y[7] = se * fmaxf(bhi(hs.w) * scB.w + shB.w, 0.f) + a[7];
    uint4 o;
    o.x = (unsigned)f2bf(y[0]) | ((unsigned)f2bf(y[1]) << 16);
    o.y = (unsigned)f2bf(y[2]) | ((unsigned)f2bf(y[3]) << 16);
    o.z = (unsigned)f2bf(y[4]) | ((unsigned)f2bf(y[5]) << 16);
    o.w = (unsigned)f2bf(y[6]) | ((unsigned)f2bf(y[7]) << 16);
    *(uint4*)(out + (size_t)n * HD + c0) = o;
}

// ---------------------------------------------------------------------------
// Fused mean-pool + head, BN on the fly.
__global__ __launch_bounds__(256) void pool_head_kernel(
    const ushort_t* __restrict__ z, const int* __restrict__ batch,
    const float* __restrict__ sscale, const float* __restrict__ sshift,
    const float* __restrict__ Wp1, const float* __restrict__ bp1,
    const float* __restrict__ Wp2, const float* __restrict__ bp2,
    float* __restrict__ out)
{
    __shared__ float poolw[4][HD];
    __shared__ float pool[HD];
    __shared__ float red[128];
    __shared__ int seg[2];
    const int g = blockIdx.x;
    const int t = threadIdx.x;
    const int w = t >> 6;
    const int L = t & 63;
    if (t == 0) {
        int lo = 0, hi = NN;
        while (lo < hi) { const int m = (lo + hi) >> 1; if (batch[m] < g) lo = m + 1; else hi = m; }
        seg[0] = lo;
        hi = NN;
        while (lo < hi) { const int m = (lo + hi) >> 1; if (batch[m] < g + 1) lo = m + 1; else hi = m; }
        seg[1] = lo;
    }
    __syncthreads();
    const int start = seg[0], end = seg[1];
    const int c0 = L * 4;
    const float4 sc = *(const float4*)(sscale + c0);
    const float4 sh = *(const float4*)(sshift + c0);
    float a0 = 0.f, a1 = 0.f, a2 = 0.f, a3 = 0.f;
    float b0 = 0.f, b1 = 0.f, b2 = 0.f, b3 = 0.f;
    int r = start + w;
    for (; r + 4 < end; r += 8) {
        const ushort4 u = *(const ushort4*)(z + (size_t)r * HD + c0);
        const ushort4 v = *(const ushort4*)(z + (size_t)(r + 4) * HD + c0);
        a0 += fmaxf(bf2f(u.x) * sc.x + sh.x, 0.f);
        a1 += fmaxf(bf2f(u.y) * sc.y + sh.y, 0.f);
        a2 += fmaxf(bf2f(u.z) * sc.z + sh.z, 0.f);
        a3 += fmaxf(bf2f(u.w) * sc.w + sh.w, 0.f);
        b0 += fmaxf(bf2f(v.x) * sc.x + sh.x, 0.f);
        b1 += fmaxf(bf2f(v.y) * sc.y + sh.y, 0.f);
        b2 += fmaxf(bf2f(v.z) * sc.z + sh.z, 0.f);
        b3 += fmaxf(bf2f(v.w) * sc.w + sh.w, 0.f);
    }
    if (r < end) {
        const ushort4 u = *(const ushort4*)(z + (size_t)r * HD + c0);
        a0 += fmaxf(bf2f(u.x) * sc.x + sh.x, 0.f);
        a1 += fmaxf(bf2f(u.y) * sc.y + sh.y, 0.f);
        a2 += fmaxf(bf2f(u.z) * sc.z + sh.z, 0.f);
        a3 += fmaxf(bf2f(u.w) * sc.w + sh.w, 0.f);
    }
    poolw[w][c0 + 0] = a0 + b0;
    poolw[w][c0 + 1] = a1 + b1;
    poolw[w][c0 + 2] = a2 + b2;
    poolw[w][c0 + 3] = a3 + b3;
    __syncthreads();
    const float invC = 1.0f / (float)max(end - start, 1);
    pool[t] = (poolw[0][t] + poolw[1][t] + poolw[2][t] + poolw[3][t]) * invC;
    __syncthreads();
    if (t < 128) {
        float acc = 0.f;
#pragma unroll 4
        for (int k = 0; k < HD; ++k)
            acc += pool[k] * Wp1[k * 128 + t];
        red[t] = fmaxf(acc + bp1[t], 0.f) * Wp2[t];
    }
    __syncthreads();
    for (int sft = 64; sft > 0; sft >>= 1) {
        if (t < sft) red[t] += red[t + sft];
        __syncthreads();
    }
    if (t == 0) out[g] = red[0] + bp2[0];
}

// ---------------------------------------------------------------------------
extern "C" void kernel_launch(void* const* d_in, const int* in_sizes, int n_in,
                              void* d_out, int out_size, void* d_ws, size_t ws_size,
                              hipStream_t stream)
{
    const float* x     = (const float*)d_in[0];
    const int*   ei    = (const int*)  d_in[1];
    const int*   batch = (const int*)  d_in[2];
    const float* W_in  = (const float*)d_in[3];
    const float* b_in  = (const float*)d_in[4];
    const float* eps   = (const float*)d_in[5];
    const float* W1    = (const float*)d_in[6];
    const float* b1    = (const float*)d_in[7];
    const float* W2    = (const float*)d_in[8];
    const float* b2    = (const float*)d_in[9];
    const float* gamma = (const float*)d_in[10];
    const float* beta  = (const float*)d_in[11];
    const float* Wp1   = (const float*)d_in[12];
    const float* bp1   = (const float*)d_in[13];
    const float* Wp2   = (const float*)d_in[14];
    const float* bp2   = (const float*)d_in[15];

    const int* srcIdx = ei;
    const int* dstIdx = ei + EE;

    // ---- workspace layout ----
    char* p = (char*)d_ws;
    ushort_t* zbuf    = (ushort_t*)p;  p += (size_t)NP * HD  * 2;   // pre-BN acts
    ushort_t* abuf    = (ushort_t*)p;  p += (size_t)NP * HD  * 2;   // aggregate out
    ushort_t* W1P     = (ushort_t*)p;  p += (size_t)NL * HD2 * HD * 2;   // packed
    ushort_t* W2P     = (ushort_t*)p;  p += (size_t)NL * HD * HD2 * 2;   // packed
    ushort_t* WinP    = (ushort_t*)p;  p += (size_t)HD * DIN * 2;        // packed
    int* deg          = (int*)p;       p += (size_t)NN * 4;
    int* partial      = (int*)p;       p += (size_t)NN * 4;
    int* bsums        = (int*)p;       p += 512 * 4;
    int* offs         = (int*)p;       p += (size_t)NN * 4;
    int* cursor       = (int*)p;       p += (size_t)NN * 4;
    int* srcSorted    = (int*)p;       p += (size_t)EE * 4;
    float* stats      = (float*)p;     p += 2 * HD * 4;
    float* sscale     = (float*)p;     p += HD * 4;
    float* sshift     = (float*)p;     p += HD * 4;

    const int nb = (NN + 255) / 256;   // 391
    const int INPROJ_LDS = 65536;      // inproj: 64KB W (epilogue-overlaid)
    const int FUSED_LDS  = 81920;      // fused_mlp v2: 2x32KB W + hchunk + bias

    // ---- BN identity + stats zero ----
    init_bn_kernel<<<1, 256, 0, stream>>>(sscale, sshift, stats);

    // ---- weight conversion (all packed MFMA-frag order) ----
    pack_win_kernel<<<16, 256, 0, stream>>>(W_in, WinP);
    pack_w1_kernel<<<256, 256, 0, stream>>>(W1, W1P);
    pack_w2_kernel<<<256, 256, 0, stream>>>(W2, W2P);

    // ---- CSR build (once; edges layer-invariant) ----
    zero_kernel<<<(NN / 4 + 255) / 256, 256, 0, stream>>>((float*)deg, NN / 4);
    hist_kernel<<<(EE + 255) / 256, 256, 0, stream>>>(dstIdx, deg, EE);
    scan1_kernel<<<nb, 256, 0, stream>>>(deg, partial, bsums, NN);
    scan2_kernel<<<1, 512, 0, stream>>>(bsums, nb);
    scan3_kernel<<<nb, 256, 0, stream>>>(partial, bsums, offs, cursor, NN);
    scatter_kernel<<<(EE + 255) / 256, 256, 0, stream>>>(srcIdx, dstIdx, cursor, srcSorted, EE);

    // ---- input projection: zbuf = relu(x @ W_in + b_in), x read as f32 ----
    inproj_kernel<<<NP / 128, 512, INPROJ_LDS, stream>>>(x, WinP, b_in, zbuf);

    // ---- GIN layers: aggregate -> fused MLP (+stats) -> BN prep ----
    for (int l = 0; l < NL; ++l) {
        aggregate_kernel<<<NN / 8, 256, 0, stream>>>(
            zbuf, offs, deg, srcSorted, eps, l, sscale, sshift, abuf);

        fused_mlp_kernel<<<NP / 128, 512, FUSED_LDS, stream>>>(
            abuf, W1P + (size_t)l * HD2 * HD, b1 + (size_t)l * HD2,
            W2P + (size_t)l * HD * HD2, b2 + (size_t)l * HD, zbuf, stats);

        bnprep_kernel<<<1, 256, 0, stream>>>(
            stats, gamma + (size_t)l * HD, beta + (size_t)l * HD, sscale, sshift, NN);
    }

    // ---- fused mean pool + head (BN on the fly) ----
    pool_head_kernel<<<NG, 256, 0, stream>>>(zbuf, batch, sscale, sshift,
                                             Wp1, bp1, Wp2, bp2, (float*)d_out);
}